// Round 7
// baseline (86.581 us; speedup 1.0000x reference)
//
#include <hip/hip_runtime.h>
#include <hip/hip_bf16.h>

// DenseGraphSimpleOpEdgeFlow: out[b,i,f] = sum_j attn[b,i,j,f]*support[b,j,f] + support[b,i,f]
//   support = inputs @ weight  (fp32)
//   attn = mask(sigmoid(op_emb' @ attn_w + attn_b)); diagonal op_emb replaced by self_op_emb,
//   adj' = adj + I; adj'==0 -> 0, adj'==1 (SKIP) -> 1, else sigmoid.
// R7: mask folded into the GEMM as a 49th K-element: A[j,48]=off_j in {+126,-126,0},
// B[48,f]=1.0, so attn = rcp(1+exp2(acc)) with saturation handling zero/skip cases and
// the diagonal handled by staging self_op into row i. Epilogue: 4 ops/element (was ~12).
// f-remap f = wv*32+lm*2+t makes sfrag/bfrag/bias/out float2. Single-buffer LDS, sync
// staging, G_=4 -> grid 1536 (~5-6 blocks/CU): TLP replaces intra-wave pipelining.
// Requires ws_size >= 64*96*128*4 = 3,145,728 bytes (support scratch).

#define B_ 64
#define N_ 96
#define F_ 128
#define D_ 48
#define G_ 4
#define NGRP (N_ / G_)   // 24 groups -> grid = 64*24 = 1536 blocks

typedef __attribute__((ext_vector_type(8))) short short8;
typedef __attribute__((ext_vector_type(4))) float f32x4;

#if __has_builtin(__builtin_amdgcn_exp2f)
#define EXP2(x) __builtin_amdgcn_exp2f(x)
#else
#define EXP2(x) exp2f(x)
#endif

__device__ __forceinline__ unsigned bfbits(float x) {
    union { __hip_bfloat16 h; unsigned short u; } cv;
    cv.h = __float2bfloat16(x);
    return (unsigned)cv.u;
}

// ---------------- Kernel 1: support = inputs @ weight  [6144,128]@[128,128] fp32 ----------------
__global__ __launch_bounds__(256, 4) void support_kernel(
    const float* __restrict__ inputs, const float* __restrict__ weight,
    float* __restrict__ support)
{
    __shared__ float in_lds[16 * F_];
    const int tid = threadIdx.x;
    const int row0 = blockIdx.x * 16;
    ((float4*)in_lds)[tid]       = ((const float4*)(inputs + (size_t)row0 * F_))[tid];
    ((float4*)in_lds)[tid + 256] = ((const float4*)(inputs + (size_t)row0 * F_))[tid + 256];
    __syncthreads();
    const int rl = tid >> 4, f0 = (tid & 15) * 8;
    float acc[8] = {0.f,0.f,0.f,0.f,0.f,0.f,0.f,0.f};
    #pragma unroll 4
    for (int k = 0; k < F_; ++k) {
        const float a = in_lds[rl * F_ + k];
        const float4 w0 = *(const float4*)(weight + k * F_ + f0);
        const float4 w1 = *(const float4*)(weight + k * F_ + f0 + 4);
        acc[0] += a * w0.x; acc[1] += a * w0.y; acc[2] += a * w0.z; acc[3] += a * w0.w;
        acc[4] += a * w1.x; acc[5] += a * w1.y; acc[6] += a * w1.z; acc[7] += a * w1.w;
    }
    float* o = support + (size_t)(row0 + rl) * F_ + f0;
    *(float4*)o       = make_float4(acc[0], acc[1], acc[2], acc[3]);
    *(float4*)(o + 4) = make_float4(acc[4], acc[5], acc[6], acc[7]);
}

// ---------------- Kernel 2: fused attn-GEMM + mask + weighted reduce + residual ----------------
// 4 waves; wave w owns f in [32w,32w+32) with lane mapping f = w*32 + (lane&15)*2 + t.
// MFMA 16x16x32 k-slot fill d = ks*32 + (lane>>4)*8 + e, identical for A and B (physical-k
// permutation cancels). C/D (HW-verified): col = lane&15 (-> f-pair), row = (lane>>4)*4+reg (-> j).
__global__ __launch_bounds__(256, 4) void fused_kernel(
    const float* __restrict__ op_emb,
    const unsigned* __restrict__ adjw,      // raw 32-bit view of adj (int32 or int64)
    const float* __restrict__ attn_w,
    const float* __restrict__ attn_b,
    const float* __restrict__ self_op,
    const float* __restrict__ support,
    float* __restrict__ out)
{
    __shared__ __align__(16) unsigned short Atile[N_ * 64];  // 12 KB; d=48 is the mask slot

    const int tid  = threadIdx.x;
    const int lane = tid & 63;
    const int wv   = tid >> 6;      // wave 0..3
    const int lg   = lane >> 4;     // k-slot group / j-subgroup 0..3
    const int lm   = lane & 15;
    const int fb   = wv * 32 + lm * 2;   // f-pair base for this lane

    const int blk = blockIdx.x;
    const int b   = blk / NGRP;
    const int grp = blk - b * NGRP;
    const int i0  = grp * G_;

    const float kNL2E = -1.44269504088896f;   // -log2(e): exp(-x) = exp2(kNL2E*x)

    // --- adj dtype sniff: int64 little-endian has all-zero high words (values 0..4) ---
    const unsigned probe = adjw[2 * lane + 1];
    const bool use32 = __any(probe != 0);   // wave-uniform; identical across waves

    // --- B fragments (attn_w pre-scaled by -log2e; d==48 -> 1.0) + bias, float2 loads ---
    short8 bfrag[2][2];     // [t][ks]
    float  bbias[2];
    {
        const float2 bb = *(const float2*)(attn_b + fb);
        bbias[0] = bb.x * kNL2E;
        bbias[1] = bb.y * kNL2E;
        #pragma unroll
        for (int ks = 0; ks < 2; ++ks) {
            short8 v0, v1;
            #pragma unroll
            for (int e = 0; e < 8; ++e) {
                const int d = ks * 32 + lg * 8 + e;
                if (d < D_) {
                    const float2 w = *(const float2*)(attn_w + d * F_ + fb);
                    v0[e] = (short)bfbits(w.x * kNL2E);
                    v1[e] = (short)bfbits(w.y * kNL2E);
                } else {
                    const unsigned one = (d == D_) ? bfbits(1.0f) : 0u;  // mask-slot weight
                    v0[e] = (short)one;
                    v1[e] = (short)one;
                }
            }
            bfrag[0][ks] = v0;
            bfrag[1][ks] = v1;
        }
    }

    // --- support fragments, float2, once per block (layout matches C/D frag) ---
    const float* srow = support + (size_t)b * N_ * F_;
    float2 sfrag[6][4];
    #pragma unroll
    for (int mt = 0; mt < 6; ++mt)
        #pragma unroll
        for (int r = 0; r < 4; ++r)
            sfrag[mt][r] = *(const float2*)(srow + (size_t)(mt * 16 + lg * 4 + r) * F_ + fb);

    // --- zero the k-pad d in [50,64): bytes 100..127 per row, once per block ---
    for (int v = tid; v < N_ * 7; v += 256) {
        const int j = v / 7, q = v - 7 * j;
        const int byte = j * 128 + ((100 + q * 4) ^ ((j & 7) << 4));
        *(unsigned*)((char*)Atile + byte) = 0u;
    }

    #pragma unroll 1
    for (int g = 0; g < G_; ++g) {
        const int i = i0 + g;
        const size_t rb = (size_t)(b * N_ + i) * N_;
        const float* src = op_emb + rb * D_;

        // ---- stage: fp32 -> bf16 LDS (XOR-swizzled); row i <- self_op; d48 <- off_j ----
        #pragma unroll
        for (int s = 0; s < 5; ++s) {
            const int w = tid + s * 256;
            if (w < N_ * 12) {
                const int j = w / 12, c = w - 12 * j;
                const int d = c * 4;
                const float4 p = (j == i) ? *(const float4*)(self_op + d)
                                          : *(const float4*)(src + (size_t)j * D_ + d);
                const int byte = j * 128 + ((c * 8) ^ ((j & 7) << 4));
                *(uint2*)((char*)Atile + byte) =
                    make_uint2(bfbits(p.x) | (bfbits(p.y) << 16),
                               bfbits(p.z) | (bfbits(p.w) << 16));
            }
        }
        if (tid < N_) {
            const size_t idx = rb + tid;
            int a = use32 ? (int)adjw[idx] : (int)adjw[2 * idx];
            a += (tid == i) ? 1 : 0;
            // off: a==0 -> +126 (attn 0 via saturation), a==1 -> -126 (attn 1), else 0 (sigmoid)
            const float off = (a == 0) ? 126.f : ((a == 1) ? -126.f : 0.f);
            const int byte = tid * 128 + (96 ^ ((tid & 7) << 4));
            *(unsigned*)((char*)Atile + byte) = bfbits(off);
        }
        __syncthreads();

        // ---- compute ----
        float osum0 = 0.f, osum1 = 0.f;
        #pragma unroll
        for (int mt = 0; mt < 6; ++mt) {
            const int jr  = mt * 16 + lm;
            const int swz = (lm & 7) << 4;
            const char* base = (const char*)Atile + jr * 128;
            const short8 a0 = *(const short8*)(base + (( 0 + lg * 16) ^ swz));
            const short8 a1 = *(const short8*)(base + ((64 + lg * 16) ^ swz));
            f32x4 acc0 = (f32x4){bbias[0], bbias[0], bbias[0], bbias[0]};
            f32x4 acc1 = (f32x4){bbias[1], bbias[1], bbias[1], bbias[1]};
            acc0 = __builtin_amdgcn_mfma_f32_16x16x32_bf16(a0, bfrag[0][0], acc0, 0, 0, 0);
            acc0 = __builtin_amdgcn_mfma_f32_16x16x32_bf16(a1, bfrag[0][1], acc0, 0, 0, 0);
            acc1 = __builtin_amdgcn_mfma_f32_16x16x32_bf16(a0, bfrag[1][0], acc1, 0, 0, 0);
            acc1 = __builtin_amdgcn_mfma_f32_16x16x32_bf16(a1, bfrag[1][1], acc1, 0, 0, 0);
            // attn = rcp(1 + exp2(acc)); saturation encodes the mask (acc includes off_j)
            #pragma unroll
            for (int r = 0; r < 4; ++r) {
                const float s0 = __builtin_amdgcn_rcpf(1.f + EXP2(acc0[r]));
                const float s1 = __builtin_amdgcn_rcpf(1.f + EXP2(acc1[r]));
                osum0 = __builtin_fmaf(s0, sfrag[mt][r].x, osum0);
                osum1 = __builtin_fmaf(s1, sfrag[mt][r].y, osum1);
            }
        }

        // ---- reduce over the 4 lg j-subsets and store (lanes 0..15) ----
        osum0 += __shfl_xor(osum0, 16);
        osum0 += __shfl_xor(osum0, 32);
        osum1 += __shfl_xor(osum1, 16);
        osum1 += __shfl_xor(osum1, 32);
        if (lg == 0) {
            const float2 sr = *(const float2*)(srow + (size_t)i * F_ + fb);
            float2 o;
            o.x = osum0 + sr.x;
            o.y = osum1 + sr.y;
            *(float2*)(out + (size_t)(b * N_ + i) * F_ + fb) = o;
        }
        __syncthreads();
    }
}

extern "C" void kernel_launch(void* const* d_in, const int* in_sizes, int n_in,
                              void* d_out, int out_size, void* d_ws, size_t ws_size,
                              hipStream_t stream) {
    const float*    inputs  = (const float*)d_in[0];
    const unsigned* adjw    = (const unsigned*)d_in[1];
    const float*    op_emb  = (const float*)d_in[2];
    const float*    weight  = (const float*)d_in[3];
    const float*    attn_w  = (const float*)d_in[4];
    const float*    attn_b  = (const float*)d_in[5];
    const float*    self_op = (const float*)d_in[6];
    float* out     = (float*)d_out;
    float* support = (float*)d_ws;  // 6144*128 fp32 = 3,145,728 bytes

    support_kernel<<<(B_ * N_) / 16, 256, 0, stream>>>(inputs, weight, support);
    fused_kernel<<<B_ * NGRP, 256, 0, stream>>>(op_emb, adjw, attn_w, attn_b, self_op,
                                                support, out);
}

// Round 8
// 75.976 us; speedup vs baseline: 1.1396x; 1.1396x over previous
//
#include <hip/hip_runtime.h>
#include <hip/hip_bf16.h>

// DenseGraphSimpleOpEdgeFlow: out[b,i,f] = sum_j attn[b,i,j,f]*support[b,j,f] + support[b,i,f]
//   support = inputs @ weight  (fp32)
//   attn = mask(sigmoid(op_emb' @ attn_w + attn_b)); diagonal op_emb replaced by self_op_emb,
//   adj' = adj + I; adj'==0 -> 0, adj'==1 (SKIP) -> 1, else sigmoid.
// R8: phase-split + spill-free occupancy. R2-R6 sat at ~2 waves/SIMD with VALUBusy 26%
// (1 instr/15cy: ds_read->mfma->acc->exp2->rcp chains, no TLP). R7's mask-fold (49th
// K-element: A[j,48]=off_j, B[48,f]=1) is kept; its regression was the (256,4) VGPR cap
// spilling sfrag (WRITE 30MB). Here: (256,2) so sfrag stays resident; all 24 MFMAs issue
// before any epilogue (48 independent sigmoid chains); G_=8 -> grid 768 = 3 blocks/CU.
// Requires ws_size >= 64*96*128*4 = 3,145,728 bytes (support scratch).

#define B_ 64
#define N_ 96
#define F_ 128
#define D_ 48
#define G_ 8
#define NGRP (N_ / G_)   // 12 groups -> grid = 64*12 = 768 blocks = 3/CU

typedef __attribute__((ext_vector_type(8))) short short8;
typedef __attribute__((ext_vector_type(4))) float f32x4;

#if __has_builtin(__builtin_amdgcn_exp2f)
#define EXP2(x) __builtin_amdgcn_exp2f(x)
#else
#define EXP2(x) exp2f(x)
#endif

__device__ __forceinline__ unsigned bfbits(float x) {
    union { __hip_bfloat16 h; unsigned short u; } cv;
    cv.h = __float2bfloat16(x);
    return (unsigned)cv.u;
}

// ---------------- Kernel 1: support = inputs @ weight  [6144,128]@[128,128] fp32 ----------------
__global__ __launch_bounds__(256, 4) void support_kernel(
    const float* __restrict__ inputs, const float* __restrict__ weight,
    float* __restrict__ support)
{
    __shared__ float in_lds[16 * F_];
    const int tid = threadIdx.x;
    const int row0 = blockIdx.x * 16;
    ((float4*)in_lds)[tid]       = ((const float4*)(inputs + (size_t)row0 * F_))[tid];
    ((float4*)in_lds)[tid + 256] = ((const float4*)(inputs + (size_t)row0 * F_))[tid + 256];
    __syncthreads();
    const int rl = tid >> 4, f0 = (tid & 15) * 8;
    float acc[8] = {0.f,0.f,0.f,0.f,0.f,0.f,0.f,0.f};
    #pragma unroll 4
    for (int k = 0; k < F_; ++k) {
        const float a = in_lds[rl * F_ + k];
        const float4 w0 = *(const float4*)(weight + k * F_ + f0);
        const float4 w1 = *(const float4*)(weight + k * F_ + f0 + 4);
        acc[0] += a * w0.x; acc[1] += a * w0.y; acc[2] += a * w0.z; acc[3] += a * w0.w;
        acc[4] += a * w1.x; acc[5] += a * w1.y; acc[6] += a * w1.z; acc[7] += a * w1.w;
    }
    float* o = support + (size_t)(row0 + rl) * F_ + f0;
    *(float4*)o       = make_float4(acc[0], acc[1], acc[2], acc[3]);
    *(float4*)(o + 4) = make_float4(acc[4], acc[5], acc[6], acc[7]);
}

// ---------------- Kernel 2: fused attn-GEMM + mask + weighted reduce + residual ----------------
// 4 waves; wave w owns f in [32w,32w+32), lane mapping f = w*32 + (lane&15)*2 + t.
// MFMA 16x16x32 k-slot fill d = ks*32 + (lane>>4)*8 + e, identical for A and B (physical-k
// permutation cancels). C/D (HW-verified): col = lane&15 (-> f-pair), row = (lane>>4)*4+reg (-> j).
__global__ __launch_bounds__(256, 2) void fused_kernel(
    const float* __restrict__ op_emb,
    const unsigned* __restrict__ adjw,      // raw 32-bit view of adj (int32 or int64)
    const float* __restrict__ attn_w,
    const float* __restrict__ attn_b,
    const float* __restrict__ self_op,
    const float* __restrict__ support,
    float* __restrict__ out)
{
    __shared__ __align__(16) unsigned short Atile[N_ * 64];  // 12 KB; d=48 is the mask slot

    const int tid  = threadIdx.x;
    const int lane = tid & 63;
    const int wv   = tid >> 6;      // wave 0..3
    const int lg   = lane >> 4;     // k-slot group / j-subgroup 0..3
    const int lm   = lane & 15;
    const int fb   = wv * 32 + lm * 2;   // f-pair base for this lane

    const int blk = blockIdx.x;
    const int b   = blk / NGRP;
    const int grp = blk - b * NGRP;
    const int i0  = grp * G_;

    const float kNL2E = -1.44269504088896f;   // -log2(e): exp(-x) = exp2(kNL2E*x)

    // --- adj dtype sniff: int64 little-endian has all-zero high words (values 0..4) ---
    const unsigned probe = adjw[2 * lane + 1];
    const bool use32 = __any(probe != 0);   // wave-uniform; identical across waves

    // --- B fragments (attn_w pre-scaled by -log2e; d==48 -> 1.0) + bias, float2 loads ---
    short8 bfrag[2][2];     // [t][ks]
    float  bbias[2];
    {
        const float2 bb = *(const float2*)(attn_b + fb);
        bbias[0] = bb.x * kNL2E;
        bbias[1] = bb.y * kNL2E;
        #pragma unroll
        for (int ks = 0; ks < 2; ++ks) {
            short8 v0, v1;
            #pragma unroll
            for (int e = 0; e < 8; ++e) {
                const int d = ks * 32 + lg * 8 + e;
                if (d < D_) {
                    const float2 w = *(const float2*)(attn_w + d * F_ + fb);
                    v0[e] = (short)bfbits(w.x * kNL2E);
                    v1[e] = (short)bfbits(w.y * kNL2E);
                } else {
                    const unsigned one = (d == D_) ? bfbits(1.0f) : 0u;  // mask-slot weight
                    v0[e] = (short)one;
                    v1[e] = (short)one;
                }
            }
            bfrag[0][ks] = v0;
            bfrag[1][ks] = v1;
        }
    }

    // --- support fragments, float2, once per block (layout matches C/D frag) ---
    const float* srow = support + (size_t)b * N_ * F_;
    float2 sfrag[6][4];
    #pragma unroll
    for (int mt = 0; mt < 6; ++mt)
        #pragma unroll
        for (int r = 0; r < 4; ++r)
            sfrag[mt][r] = *(const float2*)(srow + (size_t)(mt * 16 + lg * 4 + r) * F_ + fb);

    // --- zero the k-pad d in [50,64): bytes 100..127 per row, once per block ---
    for (int v = tid; v < N_ * 7; v += 256) {
        const int j = v / 7, q = v - 7 * j;
        const int byte = j * 128 + ((100 + q * 4) ^ ((j & 7) << 4));
        *(unsigned*)((char*)Atile + byte) = 0u;
    }

    #pragma unroll 1
    for (int g = 0; g < G_; ++g) {
        const int i = i0 + g;
        const size_t rb = (size_t)(b * N_ + i) * N_;
        const float* src = op_emb + rb * D_;

        // ---- stage: fp32 -> bf16 LDS (XOR-swizzled); row i <- self_op; d48 <- off_j ----
        float4 ld[5];
        #pragma unroll
        for (int s = 0; s < 5; ++s) {
            const int w = tid + s * 256;
            if (w < N_ * 12) {
                const int j = w / 12, c = w - 12 * j;
                const int d = c * 4;
                ld[s] = (j == i) ? *(const float4*)(self_op + d)
                                 : *(const float4*)(src + (size_t)j * D_ + d);
            }
        }
        int araw = 0;
        if (tid < N_) {
            const size_t idx = rb + tid;
            araw = use32 ? (int)adjw[idx] : (int)adjw[2 * idx];
            araw += (tid == i) ? 1 : 0;
        }
        #pragma unroll
        for (int s = 0; s < 5; ++s) {
            const int w = tid + s * 256;
            if (w < N_ * 12) {
                const int j = w / 12, c = w - 12 * j;
                const int byte = j * 128 + ((c * 8) ^ ((j & 7) << 4));
                *(uint2*)((char*)Atile + byte) =
                    make_uint2(bfbits(ld[s].x) | (bfbits(ld[s].y) << 16),
                               bfbits(ld[s].z) | (bfbits(ld[s].w) << 16));
            }
        }
        if (tid < N_) {
            // off: a'==0 -> +126 (attn 0 via exp2 saturation), a'==1 -> -126 (attn 1), else 0
            const float off = (araw == 0) ? 126.f : ((araw == 1) ? -126.f : 0.f);
            const int byte = tid * 128 + (96 ^ ((tid & 7) << 4));
            *(unsigned*)((char*)Atile + byte) = bfbits(off);
        }
        __syncthreads();

        // ---- phase A: all 24 MFMAs (6 independent mt-chains, accs stay live) ----
        f32x4 acc[6][2];
        #pragma unroll
        for (int mt = 0; mt < 6; ++mt) {
            const int jr  = mt * 16 + lm;
            const int swz = (lm & 7) << 4;
            const char* base = (const char*)Atile + jr * 128;
            const short8 a0 = *(const short8*)(base + (( 0 + lg * 16) ^ swz));
            const short8 a1 = *(const short8*)(base + ((64 + lg * 16) ^ swz));
            f32x4 c0 = (f32x4){bbias[0], bbias[0], bbias[0], bbias[0]};
            f32x4 c1 = (f32x4){bbias[1], bbias[1], bbias[1], bbias[1]};
            c0 = __builtin_amdgcn_mfma_f32_16x16x32_bf16(a0, bfrag[0][0], c0, 0, 0, 0);
            c0 = __builtin_amdgcn_mfma_f32_16x16x32_bf16(a1, bfrag[0][1], c0, 0, 0, 0);
            c1 = __builtin_amdgcn_mfma_f32_16x16x32_bf16(a0, bfrag[1][0], c1, 0, 0, 0);
            c1 = __builtin_amdgcn_mfma_f32_16x16x32_bf16(a1, bfrag[1][1], c1, 0, 0, 0);
            acc[mt][0] = c0;
            acc[mt][1] = c1;
        }

        // ---- phase B: flat epilogue, 48 independent sigmoid chains ----
        // attn = rcp(1 + exp2(acc)); saturation encodes the mask (acc includes off_j)
        float osum0 = 0.f, osum1 = 0.f;
        #pragma unroll
        for (int mt = 0; mt < 6; ++mt) {
            #pragma unroll
            for (int r = 0; r < 4; ++r) {
                const float s0 = __builtin_amdgcn_rcpf(1.f + EXP2(acc[mt][0][r]));
                const float s1 = __builtin_amdgcn_rcpf(1.f + EXP2(acc[mt][1][r]));
                osum0 = __builtin_fmaf(s0, sfrag[mt][r].x, osum0);
                osum1 = __builtin_fmaf(s1, sfrag[mt][r].y, osum1);
            }
        }

        // ---- reduce over the 4 lg j-subsets and store (lanes 0..15) ----
        osum0 += __shfl_xor(osum0, 16);
        osum0 += __shfl_xor(osum0, 32);
        osum1 += __shfl_xor(osum1, 16);
        osum1 += __shfl_xor(osum1, 32);
        if (lg == 0) {
            const float2 sr = *(const float2*)(srow + (size_t)i * F_ + fb);
            float2 o;
            o.x = osum0 + sr.x;
            o.y = osum1 + sr.y;
            *(float2*)(out + (size_t)(b * N_ + i) * F_ + fb) = o;
        }
        __syncthreads();
    }
}

extern "C" void kernel_launch(void* const* d_in, const int* in_sizes, int n_in,
                              void* d_out, int out_size, void* d_ws, size_t ws_size,
                              hipStream_t stream) {
    const float*    inputs  = (const float*)d_in[0];
    const unsigned* adjw    = (const unsigned*)d_in[1];
    const float*    op_emb  = (const float*)d_in[2];
    const float*    weight  = (const float*)d_in[3];
    const float*    attn_w  = (const float*)d_in[4];
    const float*    attn_b  = (const float*)d_in[5];
    const float*    self_op = (const float*)d_in[6];
    float* out     = (float*)d_out;
    float* support = (float*)d_ws;  // 6144*128 fp32 = 3,145,728 bytes

    support_kernel<<<(B_ * N_) / 16, 256, 0, stream>>>(inputs, weight, support);
    fused_kernel<<<B_ * NGRP, 256, 0, stream>>>(op_emb, adjw, attn_w, attn_b, self_op,
                                                support, out);
}